// Round 15
// baseline (340.833 us; speedup 1.0000x reference)
//
#include <hip/hip_runtime.h>
#include <hip/hip_bf16.h>
#include <hip/hip_fp16.h>

#define B_  128
#define S_  512
#define H_  64
#define E_  64
#define G3  192   // 3*H
#define V_  4996
#define VCHUNK 32
#define CHUNK  8             // steps per LDS xw chunk
#define NCHUNK (S_ / CHUNK)  // 64
#define STOK  (S_ + CHUNK)   // scan-ordered tokens + one pad chunk

typedef float f32x4 __attribute__((ext_vector_type(4)));
typedef unsigned int u32;
typedef u32 u32x4 __attribute__((ext_vector_type(4)));
typedef _Float16 f16;
typedef f16 f16x2 __attribute__((ext_vector_type(2)));

__device__ __forceinline__ float fast_rcp(float x) {
#if __has_builtin(__builtin_amdgcn_rcpf)
    return __builtin_amdgcn_rcpf(x);
#else
    return 1.0f / x;
#endif
}
__device__ __forceinline__ float fast_exp(float x) {   // e^x
#if __has_builtin(__builtin_amdgcn_exp2f)
    return __builtin_amdgcn_exp2f(x * 1.44269504f);
#else
    return __expf(x);
#endif
}
__device__ __forceinline__ float sigmoidf_(float x) {
    return fast_rcp(1.0f + fast_exp(-x));
}
__device__ __forceinline__ float tanh_fast(float x) {
    return 1.0f - 2.0f * fast_rcp(1.0f + fast_exp(2.0f * x));
}

// acc += lo(a)*lo(b) [f16 operands, f32 math] — v_fma_mix_f32.
// Exact same numerics as (float)f16 * (float)f16 fused into f32 acc, i.e.
// bit-identical to the R10-passing fallback path, at 1 inst per element pair
// half. R14 proved HW v_dot2_f32_f16 exists but rounds worse (2.3e-2 fail);
// fma_mix gives the instruction-count win (192 vs ~400/step) with R10 math.
__device__ __forceinline__ float fmamix_lo(float acc, u32 a, u32 b) {
    asm("v_fma_mix_f32 %0, %1, %2, %0 op_sel:[0,0,0] op_sel_hi:[1,1,0]"
        : "+v"(acc) : "v"(a), "v"(b));
    return acc;
}
__device__ __forceinline__ float fmamix_hi(float acc, u32 a, u32 b) {
    asm("v_fma_mix_f32 %0, %1, %2, %0 op_sel:[1,1,0] op_sel_hi:[1,1,0]"
        : "+v"(acc) : "v"(a), "v"(b));
    return acc;
}
__device__ __forceinline__ float dotpair_(float acc, u32 a, u32 b) {
    return fmamix_hi(fmamix_lo(acc, a, b), a, b);
}

// ---------------------------------------------------------------------------
// Kernel 1: pre-project the embedding table through the input kernels (fp32).
// ---------------------------------------------------------------------------
__global__ __launch_bounds__(192) void proj_kernel(
    const float* __restrict__ emb,
    const float* __restrict__ Wf, const float* __restrict__ bif,
    const float* __restrict__ Wb, const float* __restrict__ bib,
    float* __restrict__ proj)            // [2][V][192]
{
    const int dir = blockIdx.y;
    const float* W  = dir ? Wb  : Wf;
    const float* bi = dir ? bib : bif;
    const int v0 = blockIdx.x * VCHUNK;
    const int j  = threadIdx.x;
    const int nrows = min(VCHUNK, V_ - v0);

    __shared__ __align__(16) float s_e[VCHUNK * E_];
    for (int i = j; i < nrows * E_; i += 192) s_e[i] = emb[(size_t)v0 * E_ + i];

    float wcol[E_];
    #pragma unroll
    for (int e = 0; e < E_; ++e) wcol[e] = W[e * G3 + j];
    const float bij = bi[j];
    __syncthreads();

    for (int r = 0; r < nrows; ++r) {
        const float4* x4 = (const float4*)(s_e + r * E_);
        float a0 = 0.f, a1 = 0.f, a2 = 0.f, a3 = 0.f;
        #pragma unroll
        for (int e4 = 0; e4 < 16; e4 += 4) {
            float4 h0 = x4[e4], h1 = x4[e4+1], h2 = x4[e4+2], h3 = x4[e4+3];
            a0 = fmaf(h0.x, wcol[4*e4+ 0], a0); a0 = fmaf(h0.y, wcol[4*e4+ 1], a0);
            a0 = fmaf(h0.z, wcol[4*e4+ 2], a0); a0 = fmaf(h0.w, wcol[4*e4+ 3], a0);
            a1 = fmaf(h1.x, wcol[4*e4+ 4], a1); a1 = fmaf(h1.y, wcol[4*e4+ 5], a1);
            a1 = fmaf(h1.z, wcol[4*e4+ 6], a1); a1 = fmaf(h1.w, wcol[4*e4+ 7], a1);
            a2 = fmaf(h2.x, wcol[4*e4+ 8], a2); a2 = fmaf(h2.y, wcol[4*e4+ 9], a2);
            a2 = fmaf(h2.z, wcol[4*e4+10], a2); a2 = fmaf(h2.w, wcol[4*e4+11], a2);
            a3 = fmaf(h3.x, wcol[4*e4+12], a3); a3 = fmaf(h3.y, wcol[4*e4+13], a3);
            a3 = fmaf(h3.z, wcol[4*e4+14], a3); a3 = fmaf(h3.w, wcol[4*e4+15], a3);
        }
        proj[((size_t)dir * V_ + v0 + r) * G3 + j] = ((a0 + a1) + (a2 + a3)) + bij;
    }
}

// Kernel 2: pack recurrent kernels to f16 pairs per gate column.
//   Uh[dir][j][kk] = pack_f16(U[2kk][j], U[2kk+1][j])   kk in [0,32)
__global__ void upack_kernel(const float* __restrict__ Uf,
                             const float* __restrict__ Ub,
                             u32* __restrict__ Uh)    // [2][192][32]
{
    const int dir = blockIdx.x;
    const float* U = dir ? Ub : Uf;
    u32* o = Uh + (size_t)dir * G3 * 32;
    for (int k = threadIdx.x; k < G3 * 32; k += blockDim.x) {
        const int j = k >> 5, kk = k & 31;
        f16x2 p;
        p.x = (f16)U[(2 * kk    ) * G3 + j];
        p.y = (f16)U[(2 * kk + 1) * G3 + j];
        o[(size_t)j * 32 + kk] = __builtin_bit_cast(u32, p);
    }
}

// ---------------------------------------------------------------------------
// Kernel 3: the scan. ONE WAVE per (batch row, direction). Lane u owns unit
// u; gate columns (u, u+64, u+128) computed in-lane with v_fma_mix_f32
// against f16 U columns in 96 pinned VGPRs (f32 math, R10-identical
// numerics, half the fallback's instruction count). h broadcast via one
// 128-B f16 LDS row (8 same-address b128 reads, conflict-free). xw from an
// 8-step LDS chunk (reg-staged; vm wait once per chunk). Outputs stored
// directly, coalesced, never waited on. No barriers, no shuffles.
// ---------------------------------------------------------------------------
__global__ __launch_bounds__(64)
__attribute__((amdgpu_waves_per_eu(1, 1)))
void gru_scan13(
    const int*   __restrict__ inputs,   // [B,S]
    const float* __restrict__ proj,     // [2][V][192]
    const u32*   __restrict__ Uh,       // [2][192][32] f16-pairs
    const float* __restrict__ brf, const float* __restrict__ brb,
    float* __restrict__ gru_out)        // [B,S,2H]
{
    const int b   = blockIdx.x >> 1;
    const int dir = blockIdx.x & 1;
    const int u   = threadIdx.x;           // == unit

    const float* eproj = proj + (size_t)dir * V_ * G3;
    const float* br    = dir ? brb : brf;

    __shared__ __align__(16) int   s_tok[STOK];          // scan order + pad
    __shared__ __align__(16) f16   s_h[H_];
    __shared__ __align__(16) float s_xw[2][CHUNK * G3];  // 2 x 6 KB

    for (int t = u; t < S_; t += 64)
        s_tok[t] = inputs[b * S_ + (dir ? (S_ - 1 - t) : t)];
    for (int t = S_ + u; t < STOK; t += 64) s_tok[t] = 0;  // pad -> row 0
    s_h[u] = (f16)0.0f;
    __builtin_amdgcn_wave_barrier();

    // f16-packed U columns: 3 x 8 x u32x4 = 96 VGPRs, pinned.
    u32x4 wz[8], wr[8], wc[8];
    {
        const u32x4* pz = (const u32x4*)(Uh + ((size_t)dir * G3 + u      ) * 32);
        const u32x4* pr = (const u32x4*)(Uh + ((size_t)dir * G3 + u + 64 ) * 32);
        const u32x4* pc = (const u32x4*)(Uh + ((size_t)dir * G3 + u + 128) * 32);
        #pragma unroll
        for (int k = 0; k < 8; ++k) { wz[k] = pz[k]; wr[k] = pr[k]; wc[k] = pc[k]; }
        #pragma unroll
        for (int k = 0; k < 8; ++k) {
            asm volatile("" : "+v"(wz[k]));
            asm volatile("" : "+v"(wr[k]));
            asm volatile("" : "+v"(wc[k]));
        }
    }
    const float br0 = br[u], br1 = br[u + 64], br2 = br[u + 128];
    float res = 0.0f;                      // lane u's h value

    // ---- chunk staging: 6 f32x4 per lane = one 8-step chunk ----------
    f32x4 ld[6];
    auto stage_issue = [&](int baseStep) {
        #pragma unroll
        for (int i = 0; i < 6; ++i) {
            const int idx = i * 64 + u;      // 16B slot (0..383)
            const int row = idx / 48;        // 48 slots per 192-float row
            const int off = idx - row * 48;
            const int tk  = s_tok[baseStep + row];
            ld[i] = *(const f32x4*)(eproj + (size_t)tk * G3 + off * 4);
        }
    };
    auto stage_write = [&](int nbuf) {
        #pragma unroll
        for (int i = 0; i < 6; ++i) {
            const int idx = i * 64 + u;
            *(f32x4*)(&s_xw[nbuf][idx * 4]) = ld[i];
        }
    };

    stage_issue(0);
    stage_write(0);
    __builtin_amdgcn_wave_barrier();

    float* outb = gru_out + (size_t)b * S_ * (2 * H_) + dir * H_ + u;

    for (int c = 0; c < NCHUNK; ++c) {
        const int buf = c & 1;
        stage_issue((c + 1) * CHUNK);        // next chunk loads (pad-safe)

        #pragma unroll 1
        for (int t0 = 0; t0 < CHUNK; ++t0) {
            const int t = c * CHUNK + t0;

            const int   tok = s_tok[t];                       // broadcast b32
            const float x0  = s_xw[buf][t0 * G3 + u];
            const float x1  = s_xw[buf][t0 * G3 + u + 64];
            const float x2  = s_xw[buf][t0 * G3 + u + 128];

            // h row: 8 broadcast b128 reads (same addr across lanes)
            const u32x4* h8 = (const u32x4*)s_h;
            u32x4 hv[8];
            #pragma unroll
            for (int k = 0; k < 8; ++k) hv[k] = h8[k];

            // rec = h . U[:,col]; 3 columns x 4 indep chains, v_fma_mix_f32
            float az[4] = {br0, 0, 0, 0};
            float ar_[4] = {br1, 0, 0, 0};
            float ac_[4] = {br2, 0, 0, 0};
            #pragma unroll
            for (int k = 0; k < 8; ++k) {
                const u32x4 h4 = hv[k];
                const u32x4 vz = wz[k], vr = wr[k], vc = wc[k];
                az[0]  = dotpair_(az[0],  h4.x, vz.x);
                az[1]  = dotpair_(az[1],  h4.y, vz.y);
                az[2]  = dotpair_(az[2],  h4.z, vz.z);
                az[3]  = dotpair_(az[3],  h4.w, vz.w);
                ar_[0] = dotpair_(ar_[0], h4.x, vr.x);
                ar_[1] = dotpair_(ar_[1], h4.y, vr.y);
                ar_[2] = dotpair_(ar_[2], h4.z, vr.z);
                ar_[3] = dotpair_(ar_[3], h4.w, vr.w);
                ac_[0] = dotpair_(ac_[0], h4.x, vc.x);
                ac_[1] = dotpair_(ac_[1], h4.y, vc.y);
                ac_[2] = dotpair_(ac_[2], h4.z, vc.z);
                ac_[3] = dotpair_(ac_[3], h4.w, vc.w);
            }
            const float d0 = (az[0]  + az[1])  + (az[2]  + az[3]);
            const float d1 = (ar_[0] + ar_[1]) + (ar_[2] + ar_[3]);
            const float d2 = (ac_[0] + ac_[1]) + (ac_[2] + ac_[3]);

            const float z    = sigmoidf_(x0 + d0);
            const float r    = sigmoidf_(x1 + d1);
            const float hh   = tanh_fast(fmaf(r, d2, x2));
            const float hn   = fmaf(z, res - hh, hh);
            res = (tok != 0) ? hn : res;               // mask_zero carry

            s_h[u] = (f16)res;
            __builtin_amdgcn_wave_barrier();   // write ordered before reads

            const int tt = dir ? (S_ - 1 - t) : t;
            outb[(size_t)tt * (2 * H_)] = res;         // coalesced, no wait
        }

        stage_write(buf ^ 1);   // vm wait once per 8 steps
        __builtin_amdgcn_wave_barrier();
    }
}

// x1 = sigmoid(gru_out @ w1 + b1), x2 = sigmoid(gru_out @ w2 + b2)
__global__ __launch_bounds__(256) void head_kernel(
    const float* __restrict__ gru,      // [B*S, 2H]
    const float* __restrict__ w1, const float* __restrict__ b1,
    const float* __restrict__ w2, const float* __restrict__ b2,
    float* __restrict__ x1, float* __restrict__ x2)
{
    __shared__ __align__(16) float s_w1[2 * H_];
    __shared__ __align__(16) float s_w2[2 * H_];
    const int tid = threadIdx.x;
    if (tid < 2 * H_)      s_w1[tid]          = w1[tid];
    else                   s_w2[tid - 2 * H_] = w2[tid - 2 * H_];
    __syncthreads();

    const int i = blockIdx.x * 256 + tid;
    const float4* g4 = (const float4*)(gru + (size_t)i * (2 * H_));
    float a1 = b1[0], a2 = b2[0];
    #pragma unroll
    for (int k = 0; k < (2 * H_) / 4; ++k) {
        const float4 v  = g4[k];
        const float4 q1 = ((const float4*)s_w1)[k];
        const float4 q2 = ((const float4*)s_w2)[k];
        a1 += v.x * q1.x + v.y * q1.y + v.z * q1.z + v.w * q1.w;
        a2 += v.x * q2.x + v.y * q2.y + v.z * q2.z + v.w * q2.w;
    }
    x1[i] = 1.0f / (1.0f + __expf(-a1));
    x2[i] = 1.0f / (1.0f + __expf(-a2));
}

extern "C" void kernel_launch(void* const* d_in, const int* in_sizes, int n_in,
                              void* d_out, int out_size, void* d_ws, size_t ws_size,
                              hipStream_t stream) {
    (void)in_sizes; (void)n_in; (void)ws_size; (void)out_size;

    const int*   inputs = (const int*)  d_in[0];
    const float* emb    = (const float*)d_in[1];
    const float* Wf     = (const float*)d_in[2];
    const float* Uf     = (const float*)d_in[3];
    const float* bif    = (const float*)d_in[4];
    const float* brf    = (const float*)d_in[5];
    const float* Wb     = (const float*)d_in[6];
    const float* Ub     = (const float*)d_in[7];
    const float* bib    = (const float*)d_in[8];
    const float* brb    = (const float*)d_in[9];
    const float* w1     = (const float*)d_in[10];
    const float* b1     = (const float*)d_in[11];
    const float* w2     = (const float*)d_in[12];
    const float* b2     = (const float*)d_in[13];

    float* out = (float*)d_out;
    float* x1  = out;                       // [B*S]
    float* x2  = out + (size_t)B_ * S_;     // [B*S]
    float* gru = out + (size_t)2 * B_ * S_; // [B*S, 2H]

    // workspace: proj [2][V][192] f32 (7.67 MB), then Uh [2][192][32] u32 (48 KB)
    float* proj = (float*)d_ws;
    u32*   Uh   = (u32*)(proj + (size_t)2 * V_ * G3);

    proj_kernel<<<dim3((V_ + VCHUNK - 1) / VCHUNK, 2), 192, 0, stream>>>(
        emb, Wf, bif, Wb, bib, proj);
    upack_kernel<<<2, 256, 0, stream>>>(Uf, Ub, Uh);

    gru_scan13<<<B_ * 2, 64, 0, stream>>>(inputs, proj, Uh, brf, brb, gru);

    head_kernel<<<(B_ * S_) / 256, 256, 0, stream>>>(gru, w1, b1, w2, b2, x1, x2);
}

// Round 16
// 332.936 us; speedup vs baseline: 1.0237x; 1.0237x over previous
//
#include <hip/hip_runtime.h>
#include <hip/hip_bf16.h>
#include <hip/hip_fp16.h>

#define B_  128
#define S_  512
#define H_  64
#define E_  64
#define G3  192   // 3*H
#define V_  4996
#define VCHUNK 32
#define CHUNK  4             // steps per LDS xw chunk
#define NCHUNK (S_ / CHUNK)  // 128
#define STOK  (S_ + CHUNK)   // scan-ordered tokens + one pad chunk

typedef float f32x2 __attribute__((ext_vector_type(2)));
typedef float f32x4 __attribute__((ext_vector_type(4)));
typedef unsigned int u32;

__device__ __forceinline__ float fast_rcp(float x) {
#if __has_builtin(__builtin_amdgcn_rcpf)
    return __builtin_amdgcn_rcpf(x);
#else
    return 1.0f / x;
#endif
}
__device__ __forceinline__ float fast_exp(float x) {   // e^x
#if __has_builtin(__builtin_amdgcn_exp2f)
    return __builtin_amdgcn_exp2f(x * 1.44269504f);
#else
    return __expf(x);
#endif
}
__device__ __forceinline__ float sigmoidf_(float x) {
    return fast_rcp(1.0f + fast_exp(-x));
}
__device__ __forceinline__ float tanh_fast(float x) {
    return 1.0f - 2.0f * fast_rcp(1.0f + fast_exp(2.0f * x));
}

// acc += a*b elementwise on an f32 pair — v_pk_fma_f32 (VOP3P, FULL RATE:
// it's the instruction behind MI355X's 157 TF f32 vector peak). R15 showed
// v_fma_mix_f32 is rate-limited (~4x slow) and R14 showed v_dot2_f32_f16
// rounds worse; packed f32 is the only fast path left, and it's also the
// most accurate (pure f32 math, no f16 anywhere).
__device__ __forceinline__ f32x2 pkfma(f32x2 acc, f32x2 a, f32x2 b) {
    asm("v_pk_fma_f32 %0, %1, %2, %0" : "+v"(acc) : "v"(a), "v"(b));
    return acc;
}

// ---------------------------------------------------------------------------
// Kernel 1: pre-project the embedding table through the input kernels (fp32).
// ---------------------------------------------------------------------------
__global__ __launch_bounds__(192) void proj_kernel(
    const float* __restrict__ emb,
    const float* __restrict__ Wf, const float* __restrict__ bif,
    const float* __restrict__ Wb, const float* __restrict__ bib,
    float* __restrict__ proj)            // [2][V][192]
{
    const int dir = blockIdx.y;
    const float* W  = dir ? Wb  : Wf;
    const float* bi = dir ? bib : bif;
    const int v0 = blockIdx.x * VCHUNK;
    const int j  = threadIdx.x;
    const int nrows = min(VCHUNK, V_ - v0);

    __shared__ __align__(16) float s_e[VCHUNK * E_];
    for (int i = j; i < nrows * E_; i += 192) s_e[i] = emb[(size_t)v0 * E_ + i];

    float wcol[E_];
    #pragma unroll
    for (int e = 0; e < E_; ++e) wcol[e] = W[e * G3 + j];
    const float bij = bi[j];
    __syncthreads();

    for (int r = 0; r < nrows; ++r) {
        const float4* x4 = (const float4*)(s_e + r * E_);
        float a0 = 0.f, a1 = 0.f, a2 = 0.f, a3 = 0.f;
        #pragma unroll
        for (int e4 = 0; e4 < 16; e4 += 4) {
            float4 h0 = x4[e4], h1 = x4[e4+1], h2 = x4[e4+2], h3 = x4[e4+3];
            a0 = fmaf(h0.x, wcol[4*e4+ 0], a0); a0 = fmaf(h0.y, wcol[4*e4+ 1], a0);
            a0 = fmaf(h0.z, wcol[4*e4+ 2], a0); a0 = fmaf(h0.w, wcol[4*e4+ 3], a0);
            a1 = fmaf(h1.x, wcol[4*e4+ 4], a1); a1 = fmaf(h1.y, wcol[4*e4+ 5], a1);
            a1 = fmaf(h1.z, wcol[4*e4+ 6], a1); a1 = fmaf(h1.w, wcol[4*e4+ 7], a1);
            a2 = fmaf(h2.x, wcol[4*e4+ 8], a2); a2 = fmaf(h2.y, wcol[4*e4+ 9], a2);
            a2 = fmaf(h2.z, wcol[4*e4+10], a2); a2 = fmaf(h2.w, wcol[4*e4+11], a2);
            a3 = fmaf(h3.x, wcol[4*e4+12], a3); a3 = fmaf(h3.y, wcol[4*e4+13], a3);
            a3 = fmaf(h3.z, wcol[4*e4+14], a3); a3 = fmaf(h3.w, wcol[4*e4+15], a3);
        }
        proj[((size_t)dir * V_ + v0 + r) * G3 + j] = ((a0 + a1) + (a2 + a3)) + bij;
    }
}

// Kernel 2: transpose recurrent kernels (f32): Ut[dir][j][e] = U_dir[e][j]
__global__ void utrans_kernel(const float* __restrict__ Uf,
                              const float* __restrict__ Ub,
                              float* __restrict__ Ut)   // [2][192][64]
{
    const int dir = blockIdx.x;
    const float* U = dir ? Ub : Uf;
    float* o = Ut + (size_t)dir * G3 * H_;
    for (int k = threadIdx.x; k < G3 * H_; k += blockDim.x) {
        const int j = k / H_, e = k % H_;
        o[k] = U[e * G3 + j];
    }
}

// ---------------------------------------------------------------------------
// Kernel 3: the scan. ONE WAVE per (batch row, direction). Lane u owns unit
// u; gate columns (u, u+64, u+128) computed in-lane via v_pk_fma_f32 against
// FULL-F32 U columns held in 192 pinned VGPRs (48 f32x4). h is f32 in one
// 256-B LDS row (broadcast b128 reads, conflict-free), consumed in 8-element
// blocks so live registers stay under the 256 budget. xw from a 4-step LDS
// chunk (reg-staged; vm wait once per chunk). Pure-f32 math everywhere.
// ---------------------------------------------------------------------------
__global__ __launch_bounds__(64)
__attribute__((amdgpu_waves_per_eu(1, 1)))
void gru_scan14(
    const int*   __restrict__ inputs,   // [B,S]
    const float* __restrict__ proj,     // [2][V][192]
    const float* __restrict__ Ut,       // [2][192][64] f32
    const float* __restrict__ brf, const float* __restrict__ brb,
    float* __restrict__ gru_out)        // [B,S,2H]
{
    const int b   = blockIdx.x >> 1;
    const int dir = blockIdx.x & 1;
    const int u   = threadIdx.x;           // == unit

    const float* eproj = proj + (size_t)dir * V_ * G3;
    const float* br    = dir ? brb : brf;

    __shared__ __align__(16) int   s_tok[STOK];          // scan order + pad
    __shared__ __align__(16) float s_h[H_];              // f32 h row
    __shared__ __align__(16) float s_xw[2][CHUNK * G3];  // 2 x 3 KB

    for (int t = u; t < S_; t += 64)
        s_tok[t] = inputs[b * S_ + (dir ? (S_ - 1 - t) : t)];
    for (int t = S_ + u; t < STOK; t += 64) s_tok[t] = 0;  // pad -> row 0
    s_h[u] = 0.0f;
    __builtin_amdgcn_wave_barrier();

    // f32 U columns: 3 x 16 x f32x4 = 192 VGPRs, pinned.
    f32x4 wz[16], wr[16], wc[16];
    {
        const f32x4* pz = (const f32x4*)(Ut + ((size_t)dir * G3 + u      ) * H_);
        const f32x4* pr = (const f32x4*)(Ut + ((size_t)dir * G3 + u + 64 ) * H_);
        const f32x4* pc = (const f32x4*)(Ut + ((size_t)dir * G3 + u + 128) * H_);
        #pragma unroll
        for (int k = 0; k < 16; ++k) { wz[k] = pz[k]; wr[k] = pr[k]; wc[k] = pc[k]; }
        #pragma unroll
        for (int k = 0; k < 16; ++k) {
            asm volatile("" : "+v"(wz[k]));
            asm volatile("" : "+v"(wr[k]));
            asm volatile("" : "+v"(wc[k]));
        }
    }
    const float br0 = br[u], br1 = br[u + 64], br2 = br[u + 128];
    float res = 0.0f;                      // lane u's h value

    // ---- chunk staging: 3 f32x4 per lane = one 4-step chunk ----------
    f32x4 ld[3];
    auto stage_issue = [&](int baseStep) {
        #pragma unroll
        for (int i = 0; i < 3; ++i) {
            const int idx = i * 64 + u;      // 16B slot (0..191)
            const int row = idx / 48;        // 48 slots per 192-float row
            const int off = idx - row * 48;
            const int tk  = s_tok[baseStep + row];
            ld[i] = *(const f32x4*)(eproj + (size_t)tk * G3 + off * 4);
        }
    };
    auto stage_write = [&](int nbuf) {
        #pragma unroll
        for (int i = 0; i < 3; ++i) {
            const int idx = i * 64 + u;
            *(f32x4*)(&s_xw[nbuf][idx * 4]) = ld[i];
        }
    };

    stage_issue(0);
    stage_write(0);
    __builtin_amdgcn_wave_barrier();

    float* outb = gru_out + (size_t)b * S_ * (2 * H_) + dir * H_ + u;

    for (int c = 0; c < NCHUNK; ++c) {
        const int buf = c & 1;
        stage_issue((c + 1) * CHUNK);        // next chunk loads (pad-safe)

        #pragma unroll 1
        for (int t0 = 0; t0 < CHUNK; ++t0) {
            const int t = c * CHUNK + t0;

            const int   tok = s_tok[t];                       // broadcast b32
            const float x0  = s_xw[buf][t0 * G3 + u];
            const float x1  = s_xw[buf][t0 * G3 + u + 64];
            const float x2  = s_xw[buf][t0 * G3 + u + 128];

            // rec = h . U[:,col] for 3 columns; packed f32 pairs, 2 chains
            // per gate; h consumed in 8-element blocks (2 b128 broadcast
            // reads each) to cap live registers.
            const f32x4* h4 = (const f32x4*)s_h;
            f32x2 az0 = {br0, 0.f}, az1 = {0.f, 0.f};
            f32x2 ar0 = {br1, 0.f}, ar1 = {0.f, 0.f};
            f32x2 ac0 = {br2, 0.f}, ac1 = {0.f, 0.f};
            #pragma unroll
            for (int kb = 0; kb < 8; ++kb) {
                const f32x4 h0 = h4[2 * kb];
                const f32x4 h1 = h4[2 * kb + 1];
                const f32x2 p0 = h0.xy, p1 = h0.zw, p2 = h1.xy, p3 = h1.zw;
                const f32x4 vz0 = wz[2 * kb], vz1 = wz[2 * kb + 1];
                const f32x4 vr0 = wr[2 * kb], vr1 = wr[2 * kb + 1];
                const f32x4 vc0 = wc[2 * kb], vc1 = wc[2 * kb + 1];
                az0 = pkfma(az0, p0, vz0.xy);
                az1 = pkfma(az1, p1, vz0.zw);
                az0 = pkfma(az0, p2, vz1.xy);
                az1 = pkfma(az1, p3, vz1.zw);
                ar0 = pkfma(ar0, p0, vr0.xy);
                ar1 = pkfma(ar1, p1, vr0.zw);
                ar0 = pkfma(ar0, p2, vr1.xy);
                ar1 = pkfma(ar1, p3, vr1.zw);
                ac0 = pkfma(ac0, p0, vc0.xy);
                ac1 = pkfma(ac1, p1, vc0.zw);
                ac0 = pkfma(ac0, p2, vc1.xy);
                ac1 = pkfma(ac1, p3, vc1.zw);
            }
            const f32x2 sz = az0 + az1, sr = ar0 + ar1, sc = ac0 + ac1;
            const float d0 = sz.x + sz.y;
            const float d1 = sr.x + sr.y;
            const float d2 = sc.x + sc.y;

            const float z    = sigmoidf_(x0 + d0);
            const float r    = sigmoidf_(x1 + d1);
            const float hh   = tanh_fast(fmaf(r, d2, x2));
            const float hn   = fmaf(z, res - hh, hh);
            res = (tok != 0) ? hn : res;               // mask_zero carry

            s_h[u] = res;
            __builtin_amdgcn_wave_barrier();   // write ordered before reads

            const int tt = dir ? (S_ - 1 - t) : t;
            outb[(size_t)tt * (2 * H_)] = res;         // coalesced, no wait
        }

        stage_write(buf ^ 1);   // vm wait once per 4 steps
        __builtin_amdgcn_wave_barrier();
    }
}

// x1 = sigmoid(gru_out @ w1 + b1), x2 = sigmoid(gru_out @ w2 + b2)
__global__ __launch_bounds__(256) void head_kernel(
    const float* __restrict__ gru,      // [B*S, 2H]
    const float* __restrict__ w1, const float* __restrict__ b1,
    const float* __restrict__ w2, const float* __restrict__ b2,
    float* __restrict__ x1, float* __restrict__ x2)
{
    __shared__ __align__(16) float s_w1[2 * H_];
    __shared__ __align__(16) float s_w2[2 * H_];
    const int tid = threadIdx.x;
    if (tid < 2 * H_)      s_w1[tid]          = w1[tid];
    else                   s_w2[tid - 2 * H_] = w2[tid - 2 * H_];
    __syncthreads();

    const int i = blockIdx.x * 256 + tid;
    const float4* g4 = (const float4*)(gru + (size_t)i * (2 * H_));
    float a1 = b1[0], a2 = b2[0];
    #pragma unroll
    for (int k = 0; k < (2 * H_) / 4; ++k) {
        const float4 v  = g4[k];
        const float4 q1 = ((const float4*)s_w1)[k];
        const float4 q2 = ((const float4*)s_w2)[k];
        a1 += v.x * q1.x + v.y * q1.y + v.z * q1.z + v.w * q1.w;
        a2 += v.x * q2.x + v.y * q2.y + v.z * q2.z + v.w * q2.w;
    }
    x1[i] = 1.0f / (1.0f + __expf(-a1));
    x2[i] = 1.0f / (1.0f + __expf(-a2));
}

extern "C" void kernel_launch(void* const* d_in, const int* in_sizes, int n_in,
                              void* d_out, int out_size, void* d_ws, size_t ws_size,
                              hipStream_t stream) {
    (void)in_sizes; (void)n_in; (void)ws_size; (void)out_size;

    const int*   inputs = (const int*)  d_in[0];
    const float* emb    = (const float*)d_in[1];
    const float* Wf     = (const float*)d_in[2];
    const float* Uf     = (const float*)d_in[3];
    const float* bif    = (const float*)d_in[4];
    const float* brf    = (const float*)d_in[5];
    const float* Wb     = (const float*)d_in[6];
    const float* Ub     = (const float*)d_in[7];
    const float* bib    = (const float*)d_in[8];
    const float* brb    = (const float*)d_in[9];
    const float* w1     = (const float*)d_in[10];
    const float* b1     = (const float*)d_in[11];
    const float* w2     = (const float*)d_in[12];
    const float* b2     = (const float*)d_in[13];

    float* out = (float*)d_out;
    float* x1  = out;                       // [B*S]
    float* x2  = out + (size_t)B_ * S_;     // [B*S]
    float* gru = out + (size_t)2 * B_ * S_; // [B*S, 2H]

    // workspace: proj [2][V][192] f32 (7.67 MB), then Ut [2][192][64] f32 (96 KB)
    float* proj = (float*)d_ws;
    float* Ut   = proj + (size_t)2 * V_ * G3;

    proj_kernel<<<dim3((V_ + VCHUNK - 1) / VCHUNK, 2), 192, 0, stream>>>(
        emb, Wf, bif, Wb, bib, proj);
    utrans_kernel<<<2, 256, 0, stream>>>(Uf, Ub, Ut);

    gru_scan14<<<B_ * 2, 64, 0, stream>>>(inputs, proj, Ut, brf, brb, gru);

    head_kernel<<<(B_ * S_) / 256, 256, 0, stream>>>(gru, w1, b1, w2, b2, x1, x2);
}

// Round 17
// 309.220 us; speedup vs baseline: 1.1022x; 1.0767x over previous
//
#include <hip/hip_runtime.h>
#include <hip/hip_bf16.h>

#define B_  128
#define S_  512
#define H_  64
#define E_  64
#define G3  192   // 3*H
#define V_  4996
#define VCHUNK 32
#define CHUNK  8             // steps per LDS xw chunk
#define NCHUNK (S_ / CHUNK)  // 64
#define STOK  (S_ + CHUNK)   // scan-ordered tokens + one pad chunk

typedef float f32x4 __attribute__((ext_vector_type(4)));

__device__ __forceinline__ float fast_rcp(float x) {
#if __has_builtin(__builtin_amdgcn_rcpf)
    return __builtin_amdgcn_rcpf(x);
#else
    return 1.0f / x;
#endif
}
__device__ __forceinline__ float fast_exp(float x) {   // e^x
#if __has_builtin(__builtin_amdgcn_exp2f)
    return __builtin_amdgcn_exp2f(x * 1.44269504f);
#else
    return __expf(x);
#endif
}
__device__ __forceinline__ float sigmoidf_(float x) {
    return fast_rcp(1.0f + fast_exp(-x));
}
__device__ __forceinline__ float tanh_fast(float x) {
    return 1.0f - 2.0f * fast_rcp(1.0f + fast_exp(2.0f * x));
}

// ---------------------------------------------------------------------------
// Kernel 1: pre-project the embedding table through the input kernels (fp32).
// ---------------------------------------------------------------------------
__global__ __launch_bounds__(192) void proj_kernel(
    const float* __restrict__ emb,
    const float* __restrict__ Wf, const float* __restrict__ bif,
    const float* __restrict__ Wb, const float* __restrict__ bib,
    float* __restrict__ proj)            // [2][V][192]
{
    const int dir = blockIdx.y;
    const float* W  = dir ? Wb  : Wf;
    const float* bi = dir ? bib : bif;
    const int v0 = blockIdx.x * VCHUNK;
    const int j  = threadIdx.x;
    const int nrows = min(VCHUNK, V_ - v0);

    __shared__ __align__(16) float s_e[VCHUNK * E_];
    for (int i = j; i < nrows * E_; i += 192) s_e[i] = emb[(size_t)v0 * E_ + i];

    float wcol[E_];
    #pragma unroll
    for (int e = 0; e < E_; ++e) wcol[e] = W[e * G3 + j];
    const float bij = bi[j];
    __syncthreads();

    for (int r = 0; r < nrows; ++r) {
        const float4* x4 = (const float4*)(s_e + r * E_);
        float a0 = 0.f, a1 = 0.f, a2 = 0.f, a3 = 0.f;
        #pragma unroll
        for (int e4 = 0; e4 < 16; e4 += 4) {
            float4 h0 = x4[e4], h1 = x4[e4+1], h2 = x4[e4+2], h3 = x4[e4+3];
            a0 = fmaf(h0.x, wcol[4*e4+ 0], a0); a0 = fmaf(h0.y, wcol[4*e4+ 1], a0);
            a0 = fmaf(h0.z, wcol[4*e4+ 2], a0); a0 = fmaf(h0.w, wcol[4*e4+ 3], a0);
            a1 = fmaf(h1.x, wcol[4*e4+ 4], a1); a1 = fmaf(h1.y, wcol[4*e4+ 5], a1);
            a1 = fmaf(h1.z, wcol[4*e4+ 6], a1); a1 = fmaf(h1.w, wcol[4*e4+ 7], a1);
            a2 = fmaf(h2.x, wcol[4*e4+ 8], a2); a2 = fmaf(h2.y, wcol[4*e4+ 9], a2);
            a2 = fmaf(h2.z, wcol[4*e4+10], a2); a2 = fmaf(h2.w, wcol[4*e4+11], a2);
            a3 = fmaf(h3.x, wcol[4*e4+12], a3); a3 = fmaf(h3.y, wcol[4*e4+13], a3);
            a3 = fmaf(h3.z, wcol[4*e4+14], a3); a3 = fmaf(h3.w, wcol[4*e4+15], a3);
        }
        proj[((size_t)dir * V_ + v0 + r) * G3 + j] = ((a0 + a1) + (a2 + a3)) + bij;
    }
}

// Kernel 2: transpose recurrent kernels (f32): Ut[dir][col][e] = U_dir[e][col]
__global__ void utrans_kernel(const float* __restrict__ Uf,
                              const float* __restrict__ Ub,
                              float* __restrict__ Ut)   // [2][192][64]
{
    const int dir = blockIdx.x;
    const float* U = dir ? Ub : Uf;
    float* o = Ut + (size_t)dir * G3 * H_;
    for (int k = threadIdx.x; k < G3 * H_; k += blockDim.x) {
        const int j = k / H_, e = k % H_;
        o[k] = U[e * G3 + j];
    }
}

// ---------------------------------------------------------------------------
// Kernel 3: the scan. 192 threads = 3 waves per (batch row, direction);
// thread j owns ONE gate column j (wave 0: z, wave 1: r, wave 2: c+update).
// Per-lane per-step work: 64 full-rate f32 v_fmac against f32 U column in
// 64 resident VGPRs (NO conversions — the f16 pack cost ~390 inst/step in
// the 1-wave design), 8 broadcast b128 h-reads, ~15 misc => ~90 inst.
// The 3 waves issue in parallel on 3 SIMDs. Two RAW s_barriers per step with
// lgkm-only drains (in-flight chunk-staging vmem loads are never drained —
// the R3 killer). xw from an 8-step LDS chunk; outputs stored directly by
// the c-wave (coalesced 256B, never waited on).
// ---------------------------------------------------------------------------
__global__ __launch_bounds__(192)
__attribute__((amdgpu_waves_per_eu(1, 1)))
void gru_scan15(
    const int*   __restrict__ inputs,   // [B,S]
    const float* __restrict__ proj,     // [2][V][192]
    const float* __restrict__ Ut,       // [2][192][64] f32
    const float* __restrict__ brf, const float* __restrict__ brb,
    float* __restrict__ gru_out)        // [B,S,2H]
{
    const int b   = blockIdx.x >> 1;
    const int dir = blockIdx.x & 1;
    const int j   = threadIdx.x;           // gate column 0..191
    const int wv  = j >> 6;                // 0=z, 1=r, 2=c
    const int u   = j & 63;                // unit

    const float* eproj = proj + (size_t)dir * V_ * G3;
    const float* br    = dir ? brb : brf;

    __shared__ __align__(16) int   s_tok[STOK];          // scan order + pad
    __shared__ __align__(16) float s_h[H_];              // f32 h row
    __shared__ __align__(16) float s_g[2][H_];           // z | r
    __shared__ __align__(16) float s_xw[2][CHUNK * G3];  // 2 x 6 KB

    for (int t = j; t < S_; t += 192)
        s_tok[t] = inputs[b * S_ + (dir ? (S_ - 1 - t) : t)];
    for (int t = S_ + j; t < STOK; t += 192) s_tok[t] = 0;  // pad -> row 0
    if (wv == 2) s_h[u] = 0.0f;

    // f32 U column for THIS lane only: 16 f32x4 = 64 VGPRs, pinned.
    f32x4 w[16];
    {
        const f32x4* p = (const f32x4*)(Ut + ((size_t)dir * G3 + j) * H_);
        #pragma unroll
        for (int k = 0; k < 16; ++k) w[k] = p[k];
        #pragma unroll
        for (int k = 0; k < 16; ++k) asm volatile("" : "+v"(w[k]));
    }
    const float brj = br[j];
    float res = 0.0f;                      // c-wave: unit u's h value

    // ---- chunk staging: 2 f32x4 per lane = one 8-step chunk (8*192 f32) --
    f32x4 ld[2];
    auto stage_issue = [&](int baseStep) {
        #pragma unroll
        for (int i = 0; i < 2; ++i) {
            const int idx = i * 192 + j;     // 16B slot (0..383)
            const int row = idx / 48;        // 48 slots per 192-float row
            const int off = idx - row * 48;
            const int tk  = s_tok[baseStep + row];
            ld[i] = *(const f32x4*)(eproj + (size_t)tk * G3 + off * 4);
        }
    };
    auto stage_write = [&](int nbuf) {
        #pragma unroll
        for (int i = 0; i < 2; ++i) {
            const int idx = i * 192 + j;
            *(f32x4*)(&s_xw[nbuf][idx * 4]) = ld[i];
        }
    };

    stage_issue(0);
    stage_write(0);
    __syncthreads();                       // prologue only — full sync ok

    float* outb = gru_out + (size_t)b * S_ * (2 * H_) + dir * H_ + u;

    for (int c = 0; c < NCHUNK; ++c) {
        const int buf = c & 1;
        stage_issue((c + 1) * CHUNK);      // next chunk loads stay in flight

        #pragma unroll 1
        for (int t0 = 0; t0 < CHUNK; ++t0) {
            const int t = c * CHUNK + t0;

            // (A) h from previous step visible; xw/staging writes visible.
            asm volatile("s_waitcnt lgkmcnt(0)" ::: "memory");
            __builtin_amdgcn_s_barrier();

            const int   tok = s_tok[t];                    // broadcast b32
            const float xw  = s_xw[buf][t0 * G3 + j];

            // h row: 8 broadcast b128 reads (same addr across all lanes)
            const f32x4* h4 = (const f32x4*)s_h;
            float a0 = brj, a1 = 0.f, a2 = 0.f, a3 = 0.f;
            #pragma unroll
            for (int k = 0; k < 16; k += 4) {
                const f32x4 h0 = h4[k], h1 = h4[k+1], h2 = h4[k+2], h3 = h4[k+3];
                const f32x4 w0 = w[k],  w1 = w[k+1],  w2 = w[k+2],  w3 = w[k+3];
                a0 = fmaf(h0.x, w0.x, a0); a0 = fmaf(h0.y, w0.y, a0);
                a0 = fmaf(h0.z, w0.z, a0); a0 = fmaf(h0.w, w0.w, a0);
                a1 = fmaf(h1.x, w1.x, a1); a1 = fmaf(h1.y, w1.y, a1);
                a1 = fmaf(h1.z, w1.z, a1); a1 = fmaf(h1.w, w1.w, a1);
                a2 = fmaf(h2.x, w2.x, a2); a2 = fmaf(h2.y, w2.y, a2);
                a2 = fmaf(h2.z, w2.z, a2); a2 = fmaf(h2.w, w2.w, a2);
                a3 = fmaf(h3.x, w3.x, a3); a3 = fmaf(h3.y, w3.y, a3);
                a3 = fmaf(h3.z, w3.z, a3); a3 = fmaf(h3.w, w3.w, a3);
            }
            const float d = (a0 + a1) + (a2 + a3);   // rec_j (+ bias)

            if (wv < 2) s_g[wv][u] = sigmoidf_(xw + d);   // z | r

            // (B) z,r visible; all h/xw reads of this step complete.
            asm volatile("s_waitcnt lgkmcnt(0)" ::: "memory");
            __builtin_amdgcn_s_barrier();

            if (wv == 2) {
                const float z  = s_g[0][u];
                const float r  = s_g[1][u];
                const float hh = tanh_fast(fmaf(r, d, xw));
                const float hn = fmaf(z, res - hh, hh);
                res = (tok != 0) ? hn : res;           // mask_zero carry
                s_h[u] = res;
                const int tt = dir ? (S_ - 1 - t) : t;
                outb[(size_t)tt * (2 * H_)] = res;     // coalesced, no wait
            }
        }

        stage_write(buf ^ 1);   // vm wait once per 8 steps (cross-lane pub
                                // ordered by barrier A of the next step)
    }
}

// x1 = sigmoid(gru_out @ w1 + b1), x2 = sigmoid(gru_out @ w2 + b2)
__global__ __launch_bounds__(256) void head_kernel(
    const float* __restrict__ gru,      // [B*S, 2H]
    const float* __restrict__ w1, const float* __restrict__ b1,
    const float* __restrict__ w2, const float* __restrict__ b2,
    float* __restrict__ x1, float* __restrict__ x2)
{
    __shared__ __align__(16) float s_w1[2 * H_];
    __shared__ __align__(16) float s_w2[2 * H_];
    const int tid = threadIdx.x;
    if (tid < 2 * H_)      s_w1[tid]          = w1[tid];
    else                   s_w2[tid - 2 * H_] = w2[tid - 2 * H_];
    __syncthreads();

    const int i = blockIdx.x * 256 + tid;
    const float4* g4 = (const float4*)(gru + (size_t)i * (2 * H_));
    float a1 = b1[0], a2 = b2[0];
    #pragma unroll
    for (int k = 0; k < (2 * H_) / 4; ++k) {
        const float4 v  = g4[k];
        const float4 q1 = ((const float4*)s_w1)[k];
        const float4 q2 = ((const float4*)s_w2)[k];
        a1 += v.x * q1.x + v.y * q1.y + v.z * q1.z + v.w * q1.w;
        a2 += v.x * q2.x + v.y * q2.y + v.z * q2.z + v.w * q2.w;
    }
    x1[i] = 1.0f / (1.0f + __expf(-a1));
    x2[i] = 1.0f / (1.0f + __expf(-a2));
}

extern "C" void kernel_launch(void* const* d_in, const int* in_sizes, int n_in,
                              void* d_out, int out_size, void* d_ws, size_t ws_size,
                              hipStream_t stream) {
    (void)in_sizes; (void)n_in; (void)ws_size; (void)out_size;

    const int*   inputs = (const int*)  d_in[0];
    const float* emb    = (const float*)d_in[1];
    const float* Wf     = (const float*)d_in[2];
    const float* Uf     = (const float*)d_in[3];
    const float* bif    = (const float*)d_in[4];
    const float* brf    = (const float*)d_in[5];
    const float* Wb     = (const float*)d_in[6];
    const float* Ub     = (const float*)d_in[7];
    const float* bib    = (const float*)d_in[8];
    const float* brb    = (const float*)d_in[9];
    const float* w1     = (const float*)d_in[10];
    const float* b1     = (const float*)d_in[11];
    const float* w2     = (const float*)d_in[12];
    const float* b2     = (const float*)d_in[13];

    float* out = (float*)d_out;
    float* x1  = out;                       // [B*S]
    float* x2  = out + (size_t)B_ * S_;     // [B*S]
    float* gru = out + (size_t)2 * B_ * S_; // [B*S, 2H]

    // workspace: proj [2][V][192] f32 (7.67 MB), then Ut [2][192][64] f32 (96 KB)
    float* proj = (float*)d_ws;
    float* Ut   = proj + (size_t)2 * V_ * G3;

    proj_kernel<<<dim3((V_ + VCHUNK - 1) / VCHUNK, 2), 192, 0, stream>>>(
        emb, Wf, bif, Wb, bib, proj);
    utrans_kernel<<<2, 256, 0, stream>>>(Uf, Ub, Ut);

    gru_scan15<<<B_ * 2, 192, 0, stream>>>(inputs, proj, Ut, brf, brb, gru);

    head_kernel<<<(B_ * S_) / 256, 256, 0, stream>>>(gru, w1, b1, w2, b2, x1, x2);
}